// Round 6
// baseline (1285.054 us; speedup 1.0000x reference)
//
#include <hip/hip_runtime.h>
#include <hip/hip_bf16.h>
#include <stdint.h>

#define NN 50000
#define NE 800000
#define DD 256
#define NL 4
#define NRL 4
#define KT 1280  // NRL*DD + DD (logical K of the fused GEMM)
#define KA 1024  // NRL*DD (columns stored in Abig; root block comes from Xbf)

typedef float f32x4 __attribute__((ext_vector_type(4)));
typedef __bf16 bf16x8 __attribute__((ext_vector_type(8)));
typedef __bf16 bf16x4 __attribute__((ext_vector_type(4)));
typedef unsigned short u16x4 __attribute__((ext_vector_type(4)));

static __device__ __forceinline__ unsigned short f2bf(float f) {
  __bf16 h = (__bf16)f;
  return __builtin_bit_cast(unsigned short, h);
}

static __device__ __forceinline__ u16x4 pk4(f32x4 v) {
  u16x4 o;
  o.x = f2bf(v.x); o.y = f2bf(v.y); o.z = f2bf(v.z); o.w = f2bf(v.w);
  return o;
}

// ---------------- edge preprocessing (once per call) ----------------

__global__ __launch_bounds__(256) void k_hist(const int* __restrict__ ei,
                                              const int* __restrict__ et,
                                              int* __restrict__ cntNR) {
  int e = blockIdx.x * 256 + threadIdx.x;
  if (e >= NE) return;
  int dst = ei[NE + e];
  int r = et[e];
  atomicAdd(&cntNR[dst * 4 + r], 1);
}

__global__ __launch_bounds__(256) void k_scan1(const int* __restrict__ cntNR,
                                               int* __restrict__ offs,
                                               int* __restrict__ bsum) {
  __shared__ int sd[256];
  const int t = threadIdx.x;
  const int n = blockIdx.x * 256 + t;
  int deg = 0;
  if (n < NN) {
    const int* c = cntNR + n * 4;
    deg = c[0] + c[1] + c[2] + c[3];
  }
  sd[t] = deg;
  __syncthreads();
  int val = deg;
  for (int d = 1; d < 256; d <<= 1) {
    int other = (t >= d) ? sd[t - d] : 0;
    __syncthreads();
    val += other;
    sd[t] = val;
    __syncthreads();
  }
  if (n < NN) offs[n] = val - deg;  // exclusive
  if (t == 255) bsum[blockIdx.x] = val;
}

__global__ __launch_bounds__(256) void k_scan2(const int* __restrict__ bsum,
                                               int* __restrict__ boff, int nb) {
  __shared__ int sd[256];
  const int t = threadIdx.x;
  int v = (t < nb) ? bsum[t] : 0;
  sd[t] = v;
  __syncthreads();
  int val = v;
  for (int d = 1; d < 256; d <<= 1) {
    int other = (t >= d) ? sd[t - d] : 0;
    __syncthreads();
    val += other;
    sd[t] = val;
    __syncthreads();
  }
  boff[t] = val - v;  // exclusive
}

__global__ __launch_bounds__(256) void k_scan3(int* __restrict__ offs,
                                               const int* __restrict__ boff,
                                               int* __restrict__ cursor) {
  int n = blockIdx.x * 256 + threadIdx.x;
  if (n < NN) {
    int o = offs[n] + boff[blockIdx.x];
    offs[n] = o;
    cursor[n] = o;
  }
  if (n == 0) offs[NN] = NE;
}

__global__ __launch_bounds__(256) void k_scatter(const int* __restrict__ ei,
                                                 const int* __restrict__ et,
                                                 int* __restrict__ cursor,
                                                 uint32_t* __restrict__ packed) {
  int e = blockIdx.x * 256 + threadIdx.x;
  if (e >= NE) return;
  int src = ei[e];
  int dst = ei[NE + e];
  int r = et[e];
  int pos = atomicAdd(&cursor[dst], 1);
  packed[pos] = (uint32_t)src | ((uint32_t)r << 16);  // src < 65536 ok
}

// Build WbigT[l][o][k] bf16: k<1024 -> weights[l][k>>8][k&255][o], else roots[l][k-1024][o]
__global__ __launch_bounds__(256) void k_wconv(const float* __restrict__ weights,
                                               const float* __restrict__ roots,
                                               __hip_bfloat16* __restrict__ WbigT) {
  int idx = blockIdx.x * 256 + threadIdx.x;
  if (idx >= NL * DD * KT) return;
  int l = idx / (DD * KT);
  int rem = idx - l * (DD * KT);
  int o = rem / KT;
  int k = rem - o * KT;
  float v;
  if (k < NRL * DD) {
    int r = k >> 8, i = k & 255;
    v = weights[(((size_t)(l * NRL + r) * DD) + i) * DD + o];
  } else {
    int i = k - NRL * DD;
    v = roots[((size_t)l * DD + i) * DD + o];
  }
  WbigT[idx] = __float2bfloat16(v);
}

// one-time fp32 -> bf16 cast of the input embedding (4 elems/thread)
__global__ __launch_bounds__(256) void k_cast(const float* __restrict__ X,
                                              __hip_bfloat16* __restrict__ Xbf) {
  int i = blockIdx.x * 256 + threadIdx.x;
  if (i >= NN * 64) return;
  const f32x4* Xv = (const f32x4*)X;
  ((u16x4*)Xbf)[i] = pk4(Xv[i]);
}

// ---------------- per-layer aggregation: one wave per node, pipelined bf16 gather ------

__global__ __launch_bounds__(256) void k_agg(const __hip_bfloat16* __restrict__ Xbf,
                                             const uint32_t* __restrict__ packed,
                                             const int* __restrict__ offs,
                                             const int* __restrict__ cntNR,
                                             __hip_bfloat16* __restrict__ Abig) {
  const int wid = (blockIdx.x * 256 + threadIdx.x) >> 6;
  const int lane = threadIdx.x & 63;
  if (wid >= NN) return;
  const int beg = offs[wid];
  const int end = offs[wid + 1];
  const bf16x4* __restrict__ Xv = (const bf16x4*)Xbf;

  f32x4 a0 = {0.f, 0.f, 0.f, 0.f}, a1 = a0, a2 = a0, a3 = a0;

  // depth-8 software pipeline: 8 packed loads, then 8 row-gathers in flight,
  // then accumulate (r is wave-uniform -> scalar branch)
  for (int e = beg; e < end; e += 8) {
    uint32_t pv[8];
    bf16x4 vv[8];
#pragma unroll
    for (int i = 0; i < 8; ++i) {
      int ee = e + i;
      ee = (ee < end) ? ee : (end - 1);
      pv[i] = packed[ee];
    }
#pragma unroll
    for (int i = 0; i < 8; ++i) {
      vv[i] = Xv[(int)(pv[i] & 0xFFFFu) * 64 + lane];
    }
    const int nv = end - e;
#pragma unroll
    for (int i = 0; i < 8; ++i) {
      if (i < nv) {
        int r = (int)(pv[i] >> 16);
        f32x4 v = {(float)vv[i][0], (float)vv[i][1], (float)vv[i][2], (float)vv[i][3]};
        if (r == 0) a0 += v;
        else if (r == 1) a1 += v;
        else if (r == 2) a2 += v;
        else a3 += v;
      }
    }
  }

  const int* c = cntNR + wid * 4;
  int c0 = c[0], c1 = c[1], c2 = c[2], c3 = c[3];
  float s0 = 1.0f / (float)(c0 > 1 ? c0 : 1);
  float s1 = 1.0f / (float)(c1 > 1 ? c1 : 1);
  float s2 = 1.0f / (float)(c2 > 1 ? c2 : 1);
  float s3 = 1.0f / (float)(c3 > 1 ? c3 : 1);

  u16x4* Arow = (u16x4*)(Abig + (size_t)wid * KA);
  Arow[0 * 64 + lane] = pk4(a0 * s0);
  Arow[1 * 64 + lane] = pk4(a1 * s1);
  Arow[2 * 64 + lane] = pk4(a2 * s2);
  Arow[3 * 64 + lane] = pk4(a3 * s3);
}

// ---------------- GEMM + bias + LayerNorm + ELU + residual (+ bf16 X for next layer) ----
// C[m, n] = [Abig | Xbf][m, 0:1280] @ WbigT[n, 0:1280]^T
// BM=128, BN=256. 4 waves; each wave owns 32 FULL rows (mt=0,1) x 256 cols (nt=0..15).
// NO LDS, NO barriers: A/B fragments loaded directly from global in MFMA layout.
// A read exactly once (HBM/L3); B-frags x4 redundant from L2 (tiny). LN is wave-local.

__global__ __launch_bounds__(256, 2) void k_gemm(const __hip_bfloat16* __restrict__ A,
                                                 const __hip_bfloat16* __restrict__ Xbf_in,
                                                 const __hip_bfloat16* __restrict__ Bt,
                                                 const float* __restrict__ bias,
                                                 const float* __restrict__ gamma,
                                                 const float* __restrict__ beta,
                                                 const float* __restrict__ Xin,
                                                 float* __restrict__ Xout,
                                                 __hip_bfloat16* __restrict__ Xbf_out) {
  const int tid = threadIdx.x;
  const int w = tid >> 6;
  const int lane = tid & 63;
  const int quad = lane >> 4, l15 = lane & 15;
  const int mBase = blockIdx.x * 128 + w * 32;

  // A-fragment rows for this lane (m = l15 within each 16-row tile)
  int r0 = mBase + l15;
  int r1 = r0 + 16;
  const int r0c = (r0 < NN) ? r0 : (NN - 1);  // clamp; stores guarded below
  const int r1c = (r1 < NN) ? r1 : (NN - 1);

  const char* ap0 = (const char*)A + (size_t)r0c * (KA * 2) + quad * 16;
  const char* ap1 = (const char*)A + (size_t)r1c * (KA * 2) + quad * 16;
  const char* xp0 = (const char*)Xbf_in + (size_t)r0c * (DD * 2) + quad * 16;
  const char* xp1 = (const char*)Xbf_in + (size_t)r1c * (DD * 2) + quad * 16;
  const char* bp = (const char*)Bt + (size_t)l15 * (KT * 2) + quad * 16;  // +nt*16*2560 +k0

  f32x4 acc[2][16];
#pragma unroll
  for (int i = 0; i < 2; ++i)
#pragma unroll
    for (int j = 0; j < 16; ++j) acc[i][j] = (f32x4){0.f, 0.f, 0.f, 0.f};

  // K-chunks 0..31: A part (cols 0..1023)
  for (int c = 0; c < 32; ++c) {
    const int k0 = c * 64;
    bf16x8 a0 = *(const bf16x8*)(ap0 + k0);
    bf16x8 a1 = *(const bf16x8*)(ap1 + k0);
#pragma unroll
    for (int nt = 0; nt < 16; ++nt) {
      bf16x8 b = *(const bf16x8*)(bp + nt * (16 * KT * 2) + k0);
      acc[0][nt] = __builtin_amdgcn_mfma_f32_16x16x32_bf16(a0, b, acc[0][nt], 0, 0, 0);
      acc[1][nt] = __builtin_amdgcn_mfma_f32_16x16x32_bf16(a1, b, acc[1][nt], 0, 0, 0);
    }
  }
  // K-chunks 32..39: root part (cols 1024..1279) from Xbf
#pragma unroll
  for (int c = 0; c < 8; ++c) {
    const int k0 = c * 64;
    const int kb = KA * 2 + k0;
    bf16x8 a0 = *(const bf16x8*)(xp0 + k0);
    bf16x8 a1 = *(const bf16x8*)(xp1 + k0);
#pragma unroll
    for (int nt = 0; nt < 16; ++nt) {
      bf16x8 b = *(const bf16x8*)(bp + nt * (16 * KT * 2) + kb);
      acc[0][nt] = __builtin_amdgcn_mfma_f32_16x16x32_bf16(a0, b, acc[0][nt], 0, 0, 0);
      acc[1][nt] = __builtin_amdgcn_mfma_f32_16x16x32_bf16(a1, b, acc[1][nt], 0, 0, 0);
    }
  }

  // ---- epilogue: bias, LN (wave-local: rows fully owned by this wave), ELU, residual ----
  float bv[16], gv[16], bev[16];
#pragma unroll
  for (int nt = 0; nt < 16; ++nt) {
    int n = nt * 16 + l15;
    bv[nt] = bias[n];
    gv[nt] = gamma[n];
    bev[nt] = beta[n];
  }

#pragma unroll
  for (int mt = 0; mt < 2; ++mt) {
#pragma unroll
    for (int reg = 0; reg < 4; ++reg) {
      float s = 0.f, q = 0.f;
#pragma unroll
      for (int nt = 0; nt < 16; ++nt) {
        float v = acc[mt][nt][reg] + bv[nt];
        acc[mt][nt][reg] = v;
        s += v;
        q += v * v;
      }
      // reduce across the 16 lanes of this quad (masks<16 stay in-group)
#pragma unroll
      for (int d = 1; d < 16; d <<= 1) {
        s += __shfl_xor(s, d, 64);
        q += __shfl_xor(q, d, 64);
      }
      float mean = s * (1.0f / 256.0f);
      float var = q * (1.0f / 256.0f) - mean * mean;
      float rstd = rsqrtf(var + 1e-5f);
      int m = mBase + mt * 16 + quad * 4 + reg;
      if (m < NN) {
#pragma unroll
        for (int nt = 0; nt < 16; ++nt) {
          int n = nt * 16 + l15;
          float v = (acc[mt][nt][reg] - mean) * rstd * gv[nt] + bev[nt];
          v = v > 0.0f ? v : (__expf(v) - 1.0f);
          float res = v + Xin[(size_t)m * 256 + n];
          Xout[(size_t)m * 256 + n] = res;
          Xbf_out[(size_t)m * 256 + n] = __float2bfloat16(res);
        }
      }
    }
  }
}

// ---------------- host side ----------------

extern "C" void kernel_launch(void* const* d_in, const int* in_sizes, int n_in,
                              void* d_out, int out_size, void* d_ws, size_t ws_size,
                              hipStream_t stream) {
  const float* X0 = (const float*)d_in[0];
  const float* weights = (const float*)d_in[1];
  const float* roots = (const float*)d_in[2];
  const float* biases = (const float*)d_in[3];
  const float* ln_g = (const float*)d_in[4];
  const float* ln_b = (const float*)d_in[5];
  const int* eidx = (const int*)d_in[6];
  const int* etyp = (const int*)d_in[7];
  float* out = (float*)d_out;

  char* ws = (char*)d_ws;
  size_t off = 0;
  auto alloc = [&](size_t bytes) -> char* {
    char* p = ws + off;
    off = (off + bytes + 255) & ~(size_t)255;
    return p;
  };
  __hip_bfloat16* Abig = (__hip_bfloat16*)alloc((size_t)NN * KA * 2);          // 102.4 MB
  __hip_bfloat16* WbigT = (__hip_bfloat16*)alloc((size_t)NL * DD * KT * 2);    // 2.6 MB
  float* Xb0 = (float*)alloc((size_t)NN * DD * 4);                              // 51.2 MB
  float* Xb1 = (float*)alloc((size_t)NN * DD * 4);                              // 51.2 MB
  __hip_bfloat16* Xbf0 = (__hip_bfloat16*)alloc((size_t)NN * DD * 2);           // 25.6 MB
  __hip_bfloat16* Xbf1 = (__hip_bfloat16*)alloc((size_t)NN * DD * 2);           // 25.6 MB
  int* cntNR = (int*)alloc((size_t)NN * 4 * 4);
  int* offs = (int*)alloc((size_t)(NN + 1) * 4);
  int* cursor = (int*)alloc((size_t)NN * 4);
  uint32_t* packed = (uint32_t*)alloc((size_t)NE * 4);
  int* bsum = (int*)alloc(256 * 4);
  int* boff = (int*)alloc(256 * 4);
  (void)ws_size; (void)in_sizes; (void)n_in; (void)out_size;

  (void)hipMemsetAsync(cntNR, 0, (size_t)NN * 16, stream);
  k_hist<<<(NE + 255) / 256, 256, 0, stream>>>(eidx, etyp, cntNR);
  const int NB = (NN + 255) / 256;  // 196
  k_scan1<<<NB, 256, 0, stream>>>(cntNR, offs, bsum);
  k_scan2<<<1, 256, 0, stream>>>(bsum, boff, NB);
  k_scan3<<<NB, 256, 0, stream>>>(offs, boff, cursor);
  k_scatter<<<(NE + 255) / 256, 256, 0, stream>>>(eidx, etyp, cursor, packed);
  k_wconv<<<(NL * DD * KT + 255) / 256, 256, 0, stream>>>(weights, roots, WbigT);
  k_cast<<<(NN * 64 + 255) / 256, 256, 0, stream>>>(X0, Xbf0);

  const float* Xin = X0;
  for (int l = 0; l < NL; ++l) {
    float* Xout = (l == NL - 1) ? out : ((l & 1) ? Xb1 : Xb0);
    const __hip_bfloat16* Xbin = (l & 1) ? Xbf1 : Xbf0;
    __hip_bfloat16* Xbout = (l & 1) ? Xbf0 : Xbf1;
    k_agg<<<(NN * 64 + 255) / 256, 256, 0, stream>>>(Xbin, packed, offs, cntNR, Abig);
    k_gemm<<<(NN + 127) / 128, 256, 0, stream>>>(Abig, Xbin,
                                                 WbigT + (size_t)l * DD * KT,
                                                 biases + (size_t)l * DD,
                                                 ln_g + (size_t)l * DD,
                                                 ln_b + (size_t)l * DD, Xin, Xout, Xbout);
    Xin = Xout;
  }
}

// Round 7
// 982.277 us; speedup vs baseline: 1.3082x; 1.3082x over previous
//
#include <hip/hip_runtime.h>
#include <hip/hip_bf16.h>
#include <stdint.h>

#define NN 50000
#define NE 800000
#define DD 256
#define NL 4
#define NRL 4
#define KT 1280   // NRL*DD + DD (logical K of the fused GEMM)
#define KA 1024   // NRL*DD (columns built by aggregation; root block read from Xbf)
#define BM 32     // nodes per block in k_fused
#define BPL 327680  // Bopt elements per layer = 40 chunks * 16 ntiles * 64 lanes * 8

typedef float f32x4 __attribute__((ext_vector_type(4)));
typedef __bf16 bf16x8 __attribute__((ext_vector_type(8)));
typedef __bf16 bf16x4 __attribute__((ext_vector_type(4)));
typedef unsigned short u16x4 __attribute__((ext_vector_type(4)));

static __device__ __forceinline__ unsigned short f2bf(float f) {
  __bf16 h = (__bf16)f;
  return __builtin_bit_cast(unsigned short, h);
}

static __device__ __forceinline__ u16x4 pk4(f32x4 v) {
  u16x4 o;
  o.x = f2bf(v.x); o.y = f2bf(v.y); o.z = f2bf(v.z); o.w = f2bf(v.w);
  return o;
}

// ---------------- edge preprocessing (once per call) ----------------

__global__ __launch_bounds__(256) void k_hist(const int* __restrict__ ei,
                                              const int* __restrict__ et,
                                              int* __restrict__ cntNR) {
  int e = blockIdx.x * 256 + threadIdx.x;
  if (e >= NE) return;
  int dst = ei[NE + e];
  int r = et[e];
  atomicAdd(&cntNR[dst * 4 + r], 1);
}

__global__ __launch_bounds__(256) void k_scan1(const int* __restrict__ cntNR,
                                               int* __restrict__ offs,
                                               int* __restrict__ bsum) {
  __shared__ int sd[256];
  const int t = threadIdx.x;
  const int n = blockIdx.x * 256 + t;
  int deg = 0;
  if (n < NN) {
    const int* c = cntNR + n * 4;
    deg = c[0] + c[1] + c[2] + c[3];
  }
  sd[t] = deg;
  __syncthreads();
  int val = deg;
  for (int d = 1; d < 256; d <<= 1) {
    int other = (t >= d) ? sd[t - d] : 0;
    __syncthreads();
    val += other;
    sd[t] = val;
    __syncthreads();
  }
  if (n < NN) offs[n] = val - deg;  // exclusive
  if (t == 255) bsum[blockIdx.x] = val;
}

__global__ __launch_bounds__(256) void k_scan2(const int* __restrict__ bsum,
                                               int* __restrict__ boff, int nb) {
  __shared__ int sd[256];
  const int t = threadIdx.x;
  int v = (t < nb) ? bsum[t] : 0;
  sd[t] = v;
  __syncthreads();
  int val = v;
  for (int d = 1; d < 256; d <<= 1) {
    int other = (t >= d) ? sd[t - d] : 0;
    __syncthreads();
    val += other;
    sd[t] = val;
    __syncthreads();
  }
  boff[t] = val - v;  // exclusive
}

__global__ __launch_bounds__(256) void k_scan3(int* __restrict__ offs,
                                               const int* __restrict__ boff,
                                               int* __restrict__ cursor) {
  int n = blockIdx.x * 256 + threadIdx.x;
  if (n < NN) {
    int o = offs[n] + boff[blockIdx.x];
    offs[n] = o;
    cursor[n] = o;
  }
  if (n == 0) offs[NN] = NE;
}

__global__ __launch_bounds__(256) void k_scatter(const int* __restrict__ ei,
                                                 const int* __restrict__ et,
                                                 int* __restrict__ cursor,
                                                 uint32_t* __restrict__ packed) {
  int e = blockIdx.x * 256 + threadIdx.x;
  if (e >= NE) return;
  int src = ei[e];
  int dst = ei[NE + e];
  int r = et[e];
  int pos = atomicAdd(&cursor[dst], 1);
  packed[pos] = (uint32_t)src | ((uint32_t)r << 16);  // src < 65536 ok
}

// Build Bopt in MFMA-frag-contiguous layout: [l][c(40)][ntile(16)][lane(64)][j(8)]
// value = Wlogical[o = ntile*16 + (lane&15)][k = c*32 + (lane>>4)*8 + j]
// where Wlogical[o][k] = (k<1024) ? weights[l][k>>8][k&255][o] : roots[l][k-1024][o]
__global__ __launch_bounds__(256) void k_wconv(const float* __restrict__ weights,
                                               const float* __restrict__ roots,
                                               __hip_bfloat16* __restrict__ Bopt) {
  int idx = blockIdx.x * 256 + threadIdx.x;
  if (idx >= NL * BPL) return;
  int l = idx / BPL;
  int rem = idx - l * BPL;
  int c = rem >> 13;            // 0..39
  int within = rem & 8191;
  int t = within >> 9;          // ntile 0..15
  int lane = (within >> 3) & 63;
  int j = within & 7;
  int quad = lane >> 4, l15 = lane & 15;
  int o = t * 16 + l15;
  int k = c * 32 + quad * 8 + j;
  float v;
  if (k < KA) {
    int r = k >> 8, i = k & 255;
    v = weights[(((size_t)(l * NRL + r) * DD) + i) * DD + o];
  } else {
    int i = k - KA;
    v = roots[((size_t)l * DD + i) * DD + o];
  }
  Bopt[idx] = __float2bfloat16(v);
}

// one-time fp32 -> bf16 cast of the input embedding (4 elems/thread)
__global__ __launch_bounds__(256) void k_cast(const float* __restrict__ X,
                                              __hip_bfloat16* __restrict__ Xbf) {
  int i = blockIdx.x * 256 + threadIdx.x;
  if (i >= NN * 64) return;
  const f32x4* Xv = (const f32x4*)X;
  ((u16x4*)Xbf)[i] = pk4(Xv[i]);
}

// ---------------- fused per-layer kernel: aggregate -> GEMM -> LN/ELU/residual --------
// Phase 1: 8 waves x 4 nodes: mean-aggregate in-edges per relation into LDS A-tile
//          (chunk-major [c][row][64B], 16B-slot swizzled: slot = g ^ ((row>>1)&3)).
// Phase 2: C[m,0:256] = [Atile | Xbf][m,0:1280] @ W^T with 16x16x32 MFMA;
//          wave w owns 32 cols (ntiles w*2, w*2+1) x 32 rows; B from Bopt
//          (frag-contiguous 1KB loads). Bias + two-pass LN + ELU + residual fused.

__global__ __launch_bounds__(512, 4) void k_fused(
    const __hip_bfloat16* __restrict__ Xbf,
    const uint32_t* __restrict__ packed,
    const int* __restrict__ offs,
    const int* __restrict__ cntNR,
    const __hip_bfloat16* __restrict__ Bopt,
    const float* __restrict__ bias,
    const float* __restrict__ gamma,
    const float* __restrict__ beta,
    const float* __restrict__ Xin,
    float* __restrict__ Xout,
    __hip_bfloat16* __restrict__ Xbf_out) {
  __shared__ __align__(16) char sA[32 * 2048];  // 64 KB: [chunk 0..31][row 0..31][64B]
  __shared__ float sS[32][8];
  __shared__ float sQ[32][8];

  const int tid = threadIdx.x;
  const int w = tid >> 6;       // 0..7
  const int lane = tid & 63;
  const int quad = lane >> 4, l15 = lane & 15;
  const int mBase = blockIdx.x * BM;

  // ---- phase 1: gather/mean 4 nodes per wave into LDS ----
  const bf16x4* __restrict__ Xv = (const bf16x4*)Xbf;
  for (int i = 0; i < 4; ++i) {
    const int r = w * 4 + i;          // LDS row 0..31
    const int m = mBase + r;
    const bool valid = (m < NN);
    const int mc = valid ? m : (NN - 1);
    const int beg = valid ? offs[m] : 0;
    const int end = valid ? offs[m + 1] : 0;

    f32x4 a0 = {0.f, 0.f, 0.f, 0.f}, a1 = a0, a2 = a0, a3 = a0;
    for (int e = beg; e < end; e += 8) {
      uint32_t pv[8];
      bf16x4 vv[8];
#pragma unroll
      for (int t = 0; t < 8; ++t) {
        int ee = e + t;
        ee = (ee < end) ? ee : (end - 1);
        pv[t] = packed[ee];
      }
#pragma unroll
      for (int t = 0; t < 8; ++t) {
        vv[t] = Xv[(int)(pv[t] & 0xFFFFu) * 64 + lane];
      }
      const int nv = end - e;
#pragma unroll
      for (int t = 0; t < 8; ++t) {
        if (t < nv) {
          int rel = (int)(pv[t] >> 16);  // wave-uniform
          f32x4 v = {(float)vv[t][0], (float)vv[t][1], (float)vv[t][2], (float)vv[t][3]};
          if (rel == 0) a0 += v;
          else if (rel == 1) a1 += v;
          else if (rel == 2) a2 += v;
          else a3 += v;
        }
      }
    }

    const int* cc = cntNR + mc * 4;
    int c0 = cc[0], c1 = cc[1], c2 = cc[2], c3 = cc[3];
    a0 *= 1.0f / (float)(c0 > 1 ? c0 : 1);
    a1 *= 1.0f / (float)(c1 > 1 ? c1 : 1);
    a2 *= 1.0f / (float)(c2 > 1 ? c2 : 1);
    a3 *= 1.0f / (float)(c3 > 1 ? c3 : 1);

    // swizzled LDS store: lane's 8B for relation `rel` lives in chunk
    // rel*8 + (lane>>3), logical 16B-group g=(lane>>1)&3, slot g ^ ((r>>1)&3)
    const int slot = ((lane >> 1) & 3) ^ ((r >> 1) & 3);
    const int sub = (lane & 1) * 8;
    char* base = sA + ((lane >> 3) * 2048) + r * 64 + slot * 16 + sub;
    *(u16x4*)(base + 0 * 8 * 2048) = pk4(a0);
    *(u16x4*)(base + 1 * 8 * 2048) = pk4(a1);
    *(u16x4*)(base + 2 * 8 * 2048) = pk4(a2);
    *(u16x4*)(base + 3 * 8 * 2048) = pk4(a3);
  }
  __syncthreads();

  // ---- phase 2: GEMM ----
  f32x4 acc[2][2];
#pragma unroll
  for (int i = 0; i < 2; ++i)
#pragma unroll
    for (int j = 0; j < 2; ++j) acc[i][j] = (f32x4){0.f, 0.f, 0.f, 0.f};

  const int aswz = (quad ^ ((l15 >> 1) & 3)) * 16;  // same for row l15 and l15+16
  const int aoff0 = l15 * 64 + aswz;
  const int aoff1 = (l15 + 16) * 64 + aswz;
  const char* bp0 = (const char*)Bopt + (size_t)(w * 2 + 0) * 1024 + lane * 16;
  const char* bp1 = (const char*)Bopt + (size_t)(w * 2 + 1) * 1024 + lane * 16;

#pragma unroll 2
  for (int c = 0; c < 32; ++c) {
    bf16x8 a0 = *(const bf16x8*)(sA + c * 2048 + aoff0);
    bf16x8 a1 = *(const bf16x8*)(sA + c * 2048 + aoff1);
    bf16x8 b0 = *(const bf16x8*)(bp0 + c * 16384);
    bf16x8 b1 = *(const bf16x8*)(bp1 + c * 16384);
    acc[0][0] = __builtin_amdgcn_mfma_f32_16x16x32_bf16(a0, b0, acc[0][0], 0, 0, 0);
    acc[0][1] = __builtin_amdgcn_mfma_f32_16x16x32_bf16(a0, b1, acc[0][1], 0, 0, 0);
    acc[1][0] = __builtin_amdgcn_mfma_f32_16x16x32_bf16(a1, b0, acc[1][0], 0, 0, 0);
    acc[1][1] = __builtin_amdgcn_mfma_f32_16x16x32_bf16(a1, b1, acc[1][1], 0, 0, 0);
  }
  // root chunks 32..39: A straight from Xbf (row-major)
  {
    const int rm0 = (mBase + l15 < NN) ? (mBase + l15) : (NN - 1);
    const int rm1 = (mBase + 16 + l15 < NN) ? (mBase + 16 + l15) : (NN - 1);
    const char* xr0 = (const char*)Xbf + (size_t)rm0 * (DD * 2) + quad * 16;
    const char* xr1 = (const char*)Xbf + (size_t)rm1 * (DD * 2) + quad * 16;
#pragma unroll 2
    for (int c2 = 0; c2 < 8; ++c2) {
      const int c = 32 + c2;
      bf16x8 a0 = *(const bf16x8*)(xr0 + c2 * 64);
      bf16x8 a1 = *(const bf16x8*)(xr1 + c2 * 64);
      bf16x8 b0 = *(const bf16x8*)(bp0 + c * 16384);
      bf16x8 b1 = *(const bf16x8*)(bp1 + c * 16384);
      acc[0][0] = __builtin_amdgcn_mfma_f32_16x16x32_bf16(a0, b0, acc[0][0], 0, 0, 0);
      acc[0][1] = __builtin_amdgcn_mfma_f32_16x16x32_bf16(a0, b1, acc[0][1], 0, 0, 0);
      acc[1][0] = __builtin_amdgcn_mfma_f32_16x16x32_bf16(a1, b0, acc[1][0], 0, 0, 0);
      acc[1][1] = __builtin_amdgcn_mfma_f32_16x16x32_bf16(a1, b1, acc[1][1], 0, 0, 0);
    }
  }

  // ---- epilogue: bias + two-pass LayerNorm (cross-wave via LDS) + ELU + residual ----
  float bv[2], gv[2], bev[2];
#pragma unroll
  for (int nt = 0; nt < 2; ++nt) {
    int n = w * 32 + nt * 16 + l15;
    bv[nt] = bias[n];
    gv[nt] = gamma[n];
    bev[nt] = beta[n];
  }

  // pass 1: sums
#pragma unroll
  for (int mt = 0; mt < 2; ++mt) {
#pragma unroll
    for (int reg = 0; reg < 4; ++reg) {
      float v0 = acc[mt][0][reg] + bv[0];
      float v1 = acc[mt][1][reg] + bv[1];
      acc[mt][0][reg] = v0;
      acc[mt][1][reg] = v1;
      float s = v0 + v1;
#pragma unroll
      for (int d = 1; d < 16; d <<= 1) s += __shfl_xor(s, d, 64);
      if (l15 == 0) sS[mt * 16 + quad * 4 + reg][w] = s;
    }
  }
  __syncthreads();

  // pass 2: variance around the true mean
#pragma unroll
  for (int mt = 0; mt < 2; ++mt) {
#pragma unroll
    for (int reg = 0; reg < 4; ++reg) {
      int row = mt * 16 + quad * 4 + reg;
      const float* sr = sS[row];
      float ts = (sr[0] + sr[1]) + (sr[2] + sr[3]) + (sr[4] + sr[5]) + (sr[6] + sr[7]);
      float mean = ts * (1.0f / 256.0f);
      float d0 = acc[mt][0][reg] - mean;
      float d1 = acc[mt][1][reg] - mean;
      float q = d0 * d0 + d1 * d1;
#pragma unroll
      for (int d = 1; d < 16; d <<= 1) q += __shfl_xor(q, d, 64);
      if (l15 == 0) sQ[row][w] = q;
      // stash mean in d0's slot? keep recompute below instead
    }
  }
  __syncthreads();

#pragma unroll
  for (int mt = 0; mt < 2; ++mt) {
#pragma unroll
    for (int reg = 0; reg < 4; ++reg) {
      int row = mt * 16 + quad * 4 + reg;
      const float* sr = sS[row];
      const float* qr = sQ[row];
      float ts = (sr[0] + sr[1]) + (sr[2] + sr[3]) + (sr[4] + sr[5]) + (sr[6] + sr[7]);
      float tq = (qr[0] + qr[1]) + (qr[2] + qr[3]) + (qr[4] + qr[5]) + (qr[6] + qr[7]);
      float mean = ts * (1.0f / 256.0f);
      float var = tq * (1.0f / 256.0f);
      float rstd = rsqrtf(var + 1e-5f);
      int m = mBase + row;
      if (m < NN) {
#pragma unroll
        for (int nt = 0; nt < 2; ++nt) {
          int n = w * 32 + nt * 16 + l15;
          float v = (acc[mt][nt][reg] - mean) * rstd * gv[nt] + bev[nt];
          v = v > 0.0f ? v : (__expf(v) - 1.0f);
          float res = v + Xin[(size_t)m * 256 + n];
          Xout[(size_t)m * 256 + n] = res;
          Xbf_out[(size_t)m * 256 + n] = __float2bfloat16(res);
        }
      }
    }
  }
}

// ---------------- host side ----------------

extern "C" void kernel_launch(void* const* d_in, const int* in_sizes, int n_in,
                              void* d_out, int out_size, void* d_ws, size_t ws_size,
                              hipStream_t stream) {
  const float* X0 = (const float*)d_in[0];
  const float* weights = (const float*)d_in[1];
  const float* roots = (const float*)d_in[2];
  const float* biases = (const float*)d_in[3];
  const float* ln_g = (const float*)d_in[4];
  const float* ln_b = (const float*)d_in[5];
  const int* eidx = (const int*)d_in[6];
  const int* etyp = (const int*)d_in[7];
  float* out = (float*)d_out;

  char* ws = (char*)d_ws;
  size_t off = 0;
  auto alloc = [&](size_t bytes) -> char* {
    char* p = ws + off;
    off = (off + bytes + 255) & ~(size_t)255;
    return p;
  };
  __hip_bfloat16* Bopt = (__hip_bfloat16*)alloc((size_t)NL * BPL * 2);  // 2.6 MB
  float* Xb0 = (float*)alloc((size_t)NN * DD * 4);                      // 51.2 MB
  float* Xb1 = (float*)alloc((size_t)NN * DD * 4);                      // 51.2 MB
  __hip_bfloat16* Xbf0 = (__hip_bfloat16*)alloc((size_t)NN * DD * 2);   // 25.6 MB
  __hip_bfloat16* Xbf1 = (__hip_bfloat16*)alloc((size_t)NN * DD * 2);   // 25.6 MB
  int* cntNR = (int*)alloc((size_t)NN * 4 * 4);
  int* offs = (int*)alloc((size_t)(NN + 1) * 4);
  int* cursor = (int*)alloc((size_t)NN * 4);
  uint32_t* packed = (uint32_t*)alloc((size_t)NE * 4);
  int* bsum = (int*)alloc(256 * 4);
  int* boff = (int*)alloc(256 * 4);
  (void)ws_size; (void)in_sizes; (void)n_in; (void)out_size;

  (void)hipMemsetAsync(cntNR, 0, (size_t)NN * 16, stream);
  k_hist<<<(NE + 255) / 256, 256, 0, stream>>>(eidx, etyp, cntNR);
  const int NB = (NN + 255) / 256;  // 196
  k_scan1<<<NB, 256, 0, stream>>>(cntNR, offs, bsum);
  k_scan2<<<1, 256, 0, stream>>>(bsum, boff, NB);
  k_scan3<<<NB, 256, 0, stream>>>(offs, boff, cursor);
  k_scatter<<<(NE + 255) / 256, 256, 0, stream>>>(eidx, etyp, cursor, packed);
  k_wconv<<<(NL * BPL + 255) / 256, 256, 0, stream>>>(weights, roots, Bopt);
  k_cast<<<(NN * 64 + 255) / 256, 256, 0, stream>>>(X0, Xbf0);

  const float* Xin = X0;
  const int NG = (NN + BM - 1) / BM;  // 1563
  for (int l = 0; l < NL; ++l) {
    float* Xout = (l == NL - 1) ? out : ((l & 1) ? Xb1 : Xb0);
    const __hip_bfloat16* Xbin = (l & 1) ? Xbf1 : Xbf0;
    __hip_bfloat16* Xbout = (l & 1) ? Xbf0 : Xbf1;
    k_fused<<<NG, 512, 0, stream>>>(Xbin, packed, offs, cntNR,
                                    Bopt + (size_t)l * BPL,
                                    biases + (size_t)l * DD,
                                    ln_g + (size_t)l * DD,
                                    ln_b + (size_t)l * DD, Xin, Xout, Xbout);
    Xin = Xout;
  }
}